// Round 3
// baseline (186.257 us; speedup 1.0000x reference)
//
#include <hip/hip_runtime.h>

// 10 steps of anisotropic 2D heat stencil, 48x48, B=16384.
// One 64-lane wave per image; lane (r,c) = (tid>>3, tid&7) owns a 6x6 patch
// in REGISTERS. Halo exchange via __shfl (lane +-1 horizontal, +-8 vertical).
// Frozen reflect ghosts (= rows/cols 1 and 46 of the INITIAL state) live in
// registers. LDS used only for coalesced load/store staging.

constexpr int NXY   = 48;
constexpr int CELLS = NXY * NXY;     // 2304
constexpr int NT    = 10;
constexpr int TPB   = 64;
constexpr int PS    = 6;             // patch side (8x8 lanes)
constexpr int S     = 52;            // LDS row stride (floats), 16B-friendly

__global__ __launch_bounds__(TPB, 4) void pde_heat_kernel(
    const float* __restrict__ u0,
    const float* __restrict__ aw,
    const float* __restrict__ bw,
    float* __restrict__ out)
{
    __shared__ float P[NXY * S];     // 9984 B staging buffer

    const int tid = threadIdx.x;
    const long long b = blockIdx.x;
    const float* __restrict__ u = u0 + b * CELLS;
    float*       __restrict__ o = out + b * CELLS;

    const int r = tid >> 3, c = tid & 7;
    const int r0 = r * PS, c0 = c * PS;

    // ---- per-lane coefficients (computed once; no LDS round-trip) ----
    // alpha(i) scales axis-0 diff: 0.5*dt/dx^2 = 1.152 ; beta(j): dt/dy^2 = 2.304
    const float a0 = aw[0], a1 = aw[1], a2 = aw[2];
    const float b0 = bw[0], b1 = bw[1], b2 = bw[2];
    float ca[PS], cb[PS];
    #pragma unroll
    for (int t = 0; t < PS; ++t) {
        float y = (float)(r0 + t) * (1.0f / 47.0f);
        ca[t] = 1.152f * (a0 + a1 * sinf(6.28318530717958647692f * y)
                             + a2 * sinf(12.5663706143591729539f * y));
        float x = (float)(c0 + t) * (1.0f / 47.0f);
        cb[t] = 2.304f * (b0 + b1 * cosf(6.28318530717958647692f * x)
                             + b2 * cosf(12.5663706143591729539f * x));
    }

    // ---- stage input: coalesced float4 global -> LDS ----
    const float4* __restrict__ u4 = (const float4*)u;
    #pragma unroll
    for (int k = 0; k < 9; ++k) {
        int g  = tid + k * TPB;          // 576 float4 total
        int i  = g / 12;
        int j4 = (g - i * 12) * 4;
        *(float4*)&P[i * S + j4] = u4[g];
    }
    __syncthreads();

    // ---- patch + frozen ghosts to registers ----
    float v[PS][PS];
    #pragma unroll
    for (int ii = 0; ii < PS; ++ii)
        #pragma unroll
        for (int jj = 0; jj < PS; ++jj)
            v[ii][jj] = P[(r0 + ii) * S + c0 + jj];

    float gT[PS], gB[PS], gL[PS], gR[PS];   // reflect ghosts from INITIAL state
    #pragma unroll
    for (int jj = 0; jj < PS; ++jj) {
        gT[jj] = P[1 * S + c0 + jj];        // pad row -1  = u0[1][j]
        gB[jj] = P[46 * S + c0 + jj];       // pad row 48  = u0[46][j]
    }
    #pragma unroll
    for (int ii = 0; ii < PS; ++ii) {
        gL[ii] = P[(r0 + ii) * S + 1];      // pad col -1  = u0[i][1]
        gR[ii] = P[(r0 + ii) * S + 46];     // pad col 48  = u0[i][46]
    }

    // ---- time loop: pure registers + shuffles, no LDS, no barriers ----
    for (int t = 0; t < NT; ++t) {
        float ht[PS], hb[PS], hl[PS], hr[PS];
        #pragma unroll
        for (int jj = 0; jj < PS; ++jj) {
            ht[jj] = __shfl(v[PS - 1][jj], tid - 8);   // up-neighbor's bottom row
            hb[jj] = __shfl(v[0][jj],      tid + 8);   // down-neighbor's top row
        }
        #pragma unroll
        for (int ii = 0; ii < PS; ++ii) {
            hl[ii] = __shfl(v[ii][PS - 1], tid - 1);   // left-neighbor's right col
            hr[ii] = __shfl(v[ii][0],      tid + 1);   // right-neighbor's left col
        }
        #pragma unroll
        for (int jj = 0; jj < PS; ++jj) {
            ht[jj] = (r == 0) ? gT[jj] : ht[jj];
            hb[jj] = (r == 7) ? gB[jj] : hb[jj];
        }
        #pragma unroll
        for (int ii = 0; ii < PS; ++ii) {
            hl[ii] = (c == 0) ? gL[ii] : hl[ii];
            hr[ii] = (c == 7) ? gR[ii] : hr[ii];
        }

        float up[PS];
        #pragma unroll
        for (int jj = 0; jj < PS; ++jj) up[jj] = ht[jj];
        #pragma unroll
        for (int ii = 0; ii < PS; ++ii) {
            float cur[PS];
            #pragma unroll
            for (int jj = 0; jj < PS; ++jj) cur[jj] = v[ii][jj];
            #pragma unroll
            for (int jj = 0; jj < PS; ++jj) {
                float below = (ii < PS - 1) ? v[ii + 1][jj] : hb[jj];
                float left  = (jj > 0)      ? cur[jj - 1]   : hl[ii];
                float right = (jj < PS - 1) ? cur[jj + 1]   : hr[ii];
                float uxx = (up[jj] + below) - 2.0f * cur[jj];
                float uyy = (left + right)   - 2.0f * cur[jj];
                v[ii][jj] = cur[jj] + ca[ii] * uxx + cb[jj] * uyy;
            }
            #pragma unroll
            for (int jj = 0; jj < PS; ++jj) up[jj] = cur[jj];
        }
    }

    // ---- write back: regs -> LDS -> coalesced float4 global ----
    __syncthreads();                        // staging reads done before overwrite
    #pragma unroll
    for (int ii = 0; ii < PS; ++ii)
        #pragma unroll
        for (int jj = 0; jj < PS; ++jj)
            P[(r0 + ii) * S + c0 + jj] = v[ii][jj];
    __syncthreads();

    float4* __restrict__ o4 = (float4*)o;
    #pragma unroll
    for (int k = 0; k < 9; ++k) {
        int g  = tid + k * TPB;
        int i  = g / 12;
        int j4 = (g - i * 12) * 4;
        o4[g] = *(const float4*)&P[i * S + j4];
    }
}

extern "C" void kernel_launch(void* const* d_in, const int* in_sizes, int n_in,
                              void* d_out, int out_size, void* d_ws, size_t ws_size,
                              hipStream_t stream) {
    const float* u0 = (const float*)d_in[0];
    const float* aw = (const float*)d_in[1];
    const float* bw = (const float*)d_in[2];
    float* out = (float*)d_out;

    const int B = in_sizes[0] / CELLS;   // 16384
    pde_heat_kernel<<<B, TPB, 0, stream>>>(u0, aw, bw, out);
}

// Round 4
// 116.255 us; speedup vs baseline: 1.6021x; 1.6021x over previous
//
#include <hip/hip_runtime.h>

// 10 steps of anisotropic 2D heat stencil, 48x48, B=16384.
// One 64-lane wave per image; lane (r,c)=(tid>>3, tid&7) owns a 6x6 patch in
// registers. Halo exchange via __shfl. Frozen reflect ghosts are the boundary
// lane's OWN INITIAL values (pad = interior index 1/46, which falls inside the
// boundary lane's patch): gRow/gCol, 12 regs. LDS only for load/store staging.
// amdgpu_waves_per_eu(2,4): cap the occupancy TARGET at 4 waves/EU (LDS caps
// us there anyway) so the allocator uses ~90 VGPRs instead of spilling to 64.

constexpr int NXY   = 48;
constexpr int CELLS = NXY * NXY;     // 2304
constexpr int NT    = 10;
constexpr int TPB   = 64;
constexpr int PS    = 6;             // patch side (8x8 lanes)
constexpr int S     = 52;            // LDS row stride (floats)

__global__ __launch_bounds__(TPB)
__attribute__((amdgpu_waves_per_eu(2, 4)))
void pde_heat_kernel(
    const float* __restrict__ u0,
    const float* __restrict__ aw,
    const float* __restrict__ bw,
    float* __restrict__ out)
{
    __shared__ float P[NXY * S];     // 9984 B staging buffer

    const int tid = threadIdx.x;
    const long long b = blockIdx.x;
    const float* __restrict__ u = u0 + b * CELLS;
    float*       __restrict__ o = out + b * CELLS;

    const int r = tid >> 3, c = tid & 7;
    const int r0 = r * PS, c0 = c * PS;

    // ---- per-lane coefficients ----
    // alpha(i) scales axis-0 diff: 0.5*dt/dx^2 = 1.152 ; beta(j): dt/dy^2 = 2.304
    const float a0 = aw[0], a1 = aw[1], a2 = aw[2];
    const float b0 = bw[0], b1 = bw[1], b2 = bw[2];
    float ca[PS], cb[PS];
    #pragma unroll
    for (int t = 0; t < PS; ++t) {
        float y = (float)(r0 + t) * (1.0f / 47.0f);
        ca[t] = 1.152f * (a0 + a1 * sinf(6.28318530717958647692f * y)
                             + a2 * sinf(12.5663706143591729539f * y));
        float x = (float)(c0 + t) * (1.0f / 47.0f);
        cb[t] = 2.304f * (b0 + b1 * cosf(6.28318530717958647692f * x)
                             + b2 * cosf(12.5663706143591729539f * x));
    }

    // ---- stage input: coalesced float4 global -> LDS ----
    const float4* __restrict__ u4 = (const float4*)u;
    #pragma unroll
    for (int k = 0; k < 9; ++k) {
        int g  = tid + k * TPB;          // 576 float4 total
        int i  = g / 12;
        int j4 = (g - i * 12) * 4;
        *(float4*)&P[i * S + j4] = u4[g];
    }
    __syncthreads();

    // ---- patch to registers ----
    float v[PS][PS];
    #pragma unroll
    for (int ii = 0; ii < PS; ++ii)
        #pragma unroll
        for (int jj = 0; jj < PS; ++jj)
            v[ii][jj] = P[(r0 + ii) * S + c0 + jj];

    // ---- frozen reflect ghosts = own initial values (12 regs) ----
    // r==0: top ghost = u0[1][j]  = own v[1][:];  r==7: bottom = u0[46][j] = own v[4][:]
    // c==0: left ghost = u0[i][1] = own v[:][1];  c==7: right = u0[i][46] = own v[:][4]
    float gRow[PS], gCol[PS];
    #pragma unroll
    for (int jj = 0; jj < PS; ++jj) gRow[jj] = (r == 0) ? v[1][jj] : v[4][jj];
    #pragma unroll
    for (int ii = 0; ii < PS; ++ii) gCol[ii] = (c == 0) ? v[ii][1] : v[ii][4];

    // ---- time loop: registers + shuffles only ----
    for (int t = 0; t < NT; ++t) {
        // vertical halos must be captured BEFORE any update this step
        float prev[PS], hb[PS];
        #pragma unroll
        for (int jj = 0; jj < PS; ++jj) {
            float up = __shfl(v[PS - 1][jj], tid - 8);   // up-neighbor's bottom row
            float dn = __shfl(v[0][jj],      tid + 8);   // down-neighbor's top row
            prev[jj] = (r == 0) ? gRow[jj] : up;
            hb[jj]   = (r == 7) ? gRow[jj] : dn;
        }

        #pragma unroll
        for (int ii = 0; ii < PS; ++ii) {
            // horizontal halos JIT: v[ii] not yet overwritten by any lane (lockstep)
            float hl = __shfl(v[ii][PS - 1], tid - 1);
            float hr = __shfl(v[ii][0],      tid + 1);
            hl = (c == 0) ? gCol[ii] : hl;
            hr = (c == 7) ? gCol[ii] : hr;

            float oldc[PS];
            #pragma unroll
            for (int jj = 0; jj < PS; ++jj) oldc[jj] = v[ii][jj];
            #pragma unroll
            for (int jj = 0; jj < PS; ++jj) {
                float below = (ii < PS - 1) ? v[ii + 1][jj] : hb[jj];
                float left  = (jj > 0)      ? oldc[jj - 1]  : hl;
                float right = (jj < PS - 1) ? oldc[jj + 1]  : hr;
                float uxx = (prev[jj] + below) - 2.0f * oldc[jj];
                float uyy = (left + right)     - 2.0f * oldc[jj];
                v[ii][jj] = oldc[jj] + ca[ii] * uxx + cb[jj] * uyy;
            }
            #pragma unroll
            for (int jj = 0; jj < PS; ++jj) prev[jj] = oldc[jj];
        }
    }

    // ---- write back: regs -> LDS -> coalesced float4 global ----
    __syncthreads();
    #pragma unroll
    for (int ii = 0; ii < PS; ++ii)
        #pragma unroll
        for (int jj = 0; jj < PS; ++jj)
            P[(r0 + ii) * S + c0 + jj] = v[ii][jj];
    __syncthreads();

    float4* __restrict__ o4 = (float4*)o;
    #pragma unroll
    for (int k = 0; k < 9; ++k) {
        int g  = tid + k * TPB;
        int i  = g / 12;
        int j4 = (g - i * 12) * 4;
        o4[g] = *(const float4*)&P[i * S + j4];
    }
}

extern "C" void kernel_launch(void* const* d_in, const int* in_sizes, int n_in,
                              void* d_out, int out_size, void* d_ws, size_t ws_size,
                              hipStream_t stream) {
    const float* u0 = (const float*)d_in[0];
    const float* aw = (const float*)d_in[1];
    const float* bw = (const float*)d_in[2];
    float* out = (float*)d_out;

    const int B = in_sizes[0] / CELLS;   // 16384
    pde_heat_kernel<<<B, TPB, 0, stream>>>(u0, aw, bw, out);
}

// Round 5
// 98.026 us; speedup vs baseline: 1.9001x; 1.1860x over previous
//
#include <hip/hip_runtime.h>

// 10 steps of anisotropic 2D heat stencil, 48x48, B=16384.
// One 64-lane wave per image. Lane layout 16x4: (r,c) = (tid&15, tid>>4),
// patch = 3 rows x 12 cols in registers. Vertical halo via DPP row_shr/shl:1
// with the frozen reflect ghost passed as the DPP 'old' operand (boundary
// lanes fall back to it automatically). Horizontal halo via 2 shuffles/row.
// No LDS at all: direct float4 global loads/stores (16B aligned by layout).
// Frozen ghosts = reflect pad of the INITIAL state (reference pads once).

constexpr int NXY   = 48;
constexpr int CELLS = NXY * NXY;     // 2304
constexpr int NT    = 10;
constexpr int TPB   = 64;

// lane i <- lane i-1 within each 16-lane DPP row; invalid (i%16==0) keeps oldv
__device__ __forceinline__ float dpp_up(float oldv, float src) {
    return __int_as_float(__builtin_amdgcn_update_dpp(
        __float_as_int(oldv), __float_as_int(src), 0x111, 0xF, 0xF, false));
}
// lane i <- lane i+1; invalid (i%16==15) keeps oldv
__device__ __forceinline__ float dpp_dn(float oldv, float src) {
    return __int_as_float(__builtin_amdgcn_update_dpp(
        __float_as_int(oldv), __float_as_int(src), 0x101, 0xF, 0xF, false));
}

__global__ __launch_bounds__(TPB)
__attribute__((amdgpu_waves_per_eu(2, 4)))
void pde_heat_kernel(
    const float* __restrict__ u0,
    const float* __restrict__ aw,
    const float* __restrict__ bw,
    float* __restrict__ out)
{
    const int tid = threadIdx.x;
    const int r = tid & 15;          // patch-row index (16 strips of 3 rows)
    const int c = tid >> 4;          // patch-col index (4 strips of 12 cols)
    const long long b = blockIdx.x;
    const float4* __restrict__ u4 = (const float4*)(u0 + b * CELLS);
    float4*       __restrict__ o4 = (float4*)(out + b * CELLS);

    const int fb = r * 36 + c * 3;   // float4 index of patch (row0, col0)

    // ---- direct load: 9 x global_load_dwordx4 ----
    float v[3][12];
    #pragma unroll
    for (int ii = 0; ii < 3; ++ii)
        #pragma unroll
        for (int k = 0; k < 3; ++k) {
            float4 t = u4[fb + 12 * ii + k];
            v[ii][4*k+0] = t.x; v[ii][4*k+1] = t.y;
            v[ii][4*k+2] = t.z; v[ii][4*k+3] = t.w;
        }

    // ---- coefficients (native trig; args are 2pi*(idx/47), 4pi*(idx/47)) ----
    // alpha(i) scales axis-0 diff: 0.5*dt/dx^2 = 1.152 ; beta(j): dt/dy^2 = 2.304
    const float a0 = aw[0], a1 = aw[1], a2 = aw[2];
    const float b0 = bw[0], b1 = bw[1], b2 = bw[2];
    float ca[3], cb[12];
    #pragma unroll
    for (int ii = 0; ii < 3; ++ii) {
        float y = (float)(3 * r + ii) * (1.0f / 47.0f);
        ca[ii] = 1.152f * (a0 + a1 * __sinf(6.28318530717958647692f * y)
                              + a2 * __sinf(12.5663706143591729539f * y));
    }
    #pragma unroll
    for (int jj = 0; jj < 12; ++jj) {
        float x = (float)(12 * c + jj) * (1.0f / 47.0f);
        cb[jj] = 2.304f * (b0 + b1 * __cosf(6.28318530717958647692f * x)
                              + b2 * __cosf(12.5663706143591729539f * x));
    }

    // ---- frozen reflect ghosts (from INITIAL state) ----
    // top ghost (r==0): u0 row 1  = own v[1];  bottom (r==15): u0 row 46 = 3*15+1 = own v[1]
    // left ghost (c==0): u0 col 1 = own v[:][1]; right (c==3): col 46 = 12*3+10 = own v[:][10]
    float gV[12], gH[3];
    #pragma unroll
    for (int jj = 0; jj < 12; ++jj) gV[jj] = v[1][jj];
    #pragma unroll
    for (int ii = 0; ii < 3; ++ii)  gH[ii] = (c == 0) ? v[ii][1] : v[ii][10];

    const int laneL = tid - 16, laneR = tid + 16;

    // ---- time loop: registers + DPP + 6 shuffles/step ----
    for (int t = 0; t < NT; ++t) {
        // row below patch (down-neighbor's old row 0) must be captured first
        float hb[12], prev[12];
        #pragma unroll
        for (int jj = 0; jj < 12; ++jj) hb[jj] = dpp_dn(gV[jj], v[0][jj]);
        // row above patch (up-neighbor's old row 2; v[2] is updated last, still old)
        #pragma unroll
        for (int jj = 0; jj < 12; ++jj) prev[jj] = dpp_up(gV[jj], v[2][jj]);

        #pragma unroll
        for (int ii = 0; ii < 3; ++ii) {
            float hl = __shfl(v[ii][11], laneL);
            float hr = __shfl(v[ii][0],  laneR);
            hl = (c == 0) ? gH[ii] : hl;
            hr = (c == 3) ? gH[ii] : hr;

            float oldc[12];
            #pragma unroll
            for (int jj = 0; jj < 12; ++jj) oldc[jj] = v[ii][jj];
            #pragma unroll
            for (int jj = 0; jj < 12; ++jj) {
                float below = (ii < 2)  ? v[ii + 1][jj] : hb[jj];
                float left  = (jj > 0)  ? oldc[jj - 1]  : hl;
                float right = (jj < 11) ? oldc[jj + 1]  : hr;
                float uxx = (prev[jj] + below) - 2.0f * oldc[jj];
                float uyy = (left + right)     - 2.0f * oldc[jj];
                v[ii][jj] = oldc[jj] + ca[ii] * uxx + cb[jj] * uyy;
            }
            #pragma unroll
            for (int jj = 0; jj < 12; ++jj) prev[jj] = oldc[jj];
        }
    }

    // ---- direct store: 9 x global_store_dwordx4 ----
    #pragma unroll
    for (int ii = 0; ii < 3; ++ii)
        #pragma unroll
        for (int k = 0; k < 3; ++k) {
            float4 t;
            t.x = v[ii][4*k+0]; t.y = v[ii][4*k+1];
            t.z = v[ii][4*k+2]; t.w = v[ii][4*k+3];
            o4[fb + 12 * ii + k] = t;
        }
}

extern "C" void kernel_launch(void* const* d_in, const int* in_sizes, int n_in,
                              void* d_out, int out_size, void* d_ws, size_t ws_size,
                              hipStream_t stream) {
    const float* u0 = (const float*)d_in[0];
    const float* aw = (const float*)d_in[1];
    const float* bw = (const float*)d_in[2];
    float* out = (float*)d_out;

    const int B = in_sizes[0] / CELLS;   // 16384
    pde_heat_kernel<<<B, TPB, 0, stream>>>(u0, aw, bw, out);
}

// Round 6
// 87.574 us; speedup vs baseline: 2.1269x; 1.1194x over previous
//
#include <hip/hip_runtime.h>

// 10 steps of anisotropic 2D heat stencil, 48x48, B=16384.
// Wave = image. Lane layout 16x4: (r,c) = (lane&15, lane>>4), patch = 3x12 in
// registers, stored as 6 x float2 per row so the stencil math emits packed
// v_pk_add_f32 / v_pk_fma_f32 (2 f32/lane/instr on gfx950).
// Vertical halo: DPP row shifts with frozen reflect ghost as the 'old' operand.
// Horizontal halo: 2 bpermute/row. No LDS; direct float4 global load/store.
// 4 independent waves per 256-thread block (no barriers) to fill CUs.
// Ghost ring = reflect pad of the INITIAL state, frozen across steps.

typedef float v2f __attribute__((ext_vector_type(2)));

constexpr int NXY   = 48;
constexpr int CELLS = NXY * NXY;     // 2304
constexpr int NT    = 10;
constexpr int WPB   = 4;             // waves (images) per block
constexpr int TPB   = 64 * WPB;

// lane i <- lane i-1 within each 16-lane DPP row; invalid (i%16==0) keeps oldv
__device__ __forceinline__ float dpp_up(float oldv, float src) {
    return __int_as_float(__builtin_amdgcn_update_dpp(
        __float_as_int(oldv), __float_as_int(src), 0x111, 0xF, 0xF, false));
}
// lane i <- lane i+1; invalid (i%16==15) keeps oldv
__device__ __forceinline__ float dpp_dn(float oldv, float src) {
    return __int_as_float(__builtin_amdgcn_update_dpp(
        __float_as_int(oldv), __float_as_int(src), 0x101, 0xF, 0xF, false));
}
__device__ __forceinline__ v2f dpp_up2(v2f o, v2f s) {
    v2f r; r.x = dpp_up(o.x, s.x); r.y = dpp_up(o.y, s.y); return r;
}
__device__ __forceinline__ v2f dpp_dn2(v2f o, v2f s) {
    v2f r; r.x = dpp_dn(o.x, s.x); r.y = dpp_dn(o.y, s.y); return r;
}

__global__ __launch_bounds__(TPB)
__attribute__((amdgpu_waves_per_eu(2, 4)))
void pde_heat_kernel(
    const float* __restrict__ u0,
    const float* __restrict__ aw,
    const float* __restrict__ bw,
    float* __restrict__ out)
{
    const int lane = threadIdx.x & 63;
    const int img  = blockIdx.x * WPB + (threadIdx.x >> 6);
    const int r = lane & 15;         // patch-row strip (16 strips of 3 rows)
    const int c = lane >> 4;         // patch-col strip (4 strips of 12 cols)
    const float4* __restrict__ u4 = (const float4*)(u0 + (long long)img * CELLS);
    float4*       __restrict__ o4 = (float4*)(out + (long long)img * CELLS);

    const int fb = r * 36 + c * 3;   // float4 index of patch (row0, col0)

    // ---- direct load: 9 x global_load_dwordx4 -> 6 x v2f per row ----
    v2f v[3][6];
    #pragma unroll
    for (int ii = 0; ii < 3; ++ii)
        #pragma unroll
        for (int k = 0; k < 3; ++k) {
            float4 t = u4[fb + 12 * ii + k];
            v[ii][2*k]   = (v2f){t.x, t.y};
            v[ii][2*k+1] = (v2f){t.z, t.w};
        }

    // ---- coefficients: alpha(i) scales axis-0 diff (0.5*dt/dx^2 = 1.152),
    //      beta(j) scales axis-1 diff (dt/dy^2 = 2.304); coord = idx/47 ----
    const float a0 = aw[0], a1 = aw[1], a2 = aw[2];
    const float b0 = bw[0], b1 = bw[1], b2 = bw[2];
    float ca[3];
    #pragma unroll
    for (int ii = 0; ii < 3; ++ii) {
        float y = (float)(3 * r + ii) * (1.0f / 47.0f);
        ca[ii] = 1.152f * (a0 + a1 * __sinf(6.28318530717958647692f * y)
                              + a2 * __sinf(12.5663706143591729539f * y));
    }
    v2f cb2[6];
    #pragma unroll
    for (int k = 0; k < 6; ++k) {
        float x0 = (float)(12 * c + 2 * k)     * (1.0f / 47.0f);
        float x1 = (float)(12 * c + 2 * k + 1) * (1.0f / 47.0f);
        cb2[k].x = 2.304f * (b0 + b1 * __cosf(6.28318530717958647692f * x0)
                                + b2 * __cosf(12.5663706143591729539f * x0));
        cb2[k].y = 2.304f * (b0 + b1 * __cosf(6.28318530717958647692f * x1)
                                + b2 * __cosf(12.5663706143591729539f * x1));
    }

    // ---- frozen reflect ghosts (from INITIAL state) ----
    // top (r==0): u0 row 1 = own v[1]; bottom (r==15): row 46 = 3*15+1 = own v[1]
    // left (c==0): col 1 = own elem 1 = v[ii][0].y; right (c==3): col 46 = elem 10 = v[ii][5].x
    v2f gV[6];
    #pragma unroll
    for (int k = 0; k < 6; ++k) gV[k] = v[1][k];
    float gH[3];
    #pragma unroll
    for (int ii = 0; ii < 3; ++ii) gH[ii] = (c == 0) ? v[ii][0].y : v[ii][5].x;

    const int laneL = lane - 16, laneR = lane + 16;

    // ---- time loop: registers + DPP + 6 bpermute/step, packed f32 math ----
    for (int t = 0; t < NT; ++t) {
        // capture old vertical halos before any update this step
        v2f hb[6], prev[6];
        #pragma unroll
        for (int k = 0; k < 6; ++k) hb[k]   = dpp_dn2(gV[k], v[0][k]);
        #pragma unroll
        for (int k = 0; k < 6; ++k) prev[k] = dpp_up2(gV[k], v[2][k]);

        #pragma unroll
        for (int ii = 0; ii < 3; ++ii) {
            float hl = __shfl(v[ii][5].y, laneL);   // left-neighbor's col 11
            float hr = __shfl(v[ii][0].x, laneR);   // right-neighbor's col 0
            hl = (c == 0) ? gH[ii] : hl;
            hr = (c == 3) ? gH[ii] : hr;

            v2f oldc[6];
            #pragma unroll
            for (int k = 0; k < 6; ++k) oldc[k] = v[ii][k];

            // shifted row vectors for the horizontal term
            v2f L[6], R[6];
            L[0] = (v2f){hl, oldc[0].x};
            #pragma unroll
            for (int k = 1; k < 6; ++k) L[k] = (v2f){oldc[k-1].y, oldc[k].x};
            #pragma unroll
            for (int k = 0; k < 5; ++k) R[k] = (v2f){oldc[k].y, oldc[k+1].x};
            R[5] = (v2f){oldc[5].y, hr};

            #pragma unroll
            for (int k = 0; k < 6; ++k) {
                v2f below = (ii < 2) ? v[ii + 1][k] : hb[k];
                v2f uxx = (prev[k] + below) - 2.0f * oldc[k];   // packed
                v2f uyy = (L[k] + R[k])     - 2.0f * oldc[k];   // packed
                v[ii][k] = oldc[k] + ca[ii] * uxx + cb2[k] * uyy; // packed fma
            }
            #pragma unroll
            for (int k = 0; k < 6; ++k) prev[k] = oldc[k];
        }
    }

    // ---- direct store: 9 x global_store_dwordx4 ----
    #pragma unroll
    for (int ii = 0; ii < 3; ++ii)
        #pragma unroll
        for (int k = 0; k < 3; ++k) {
            float4 t;
            t.x = v[ii][2*k].x;   t.y = v[ii][2*k].y;
            t.z = v[ii][2*k+1].x; t.w = v[ii][2*k+1].y;
            o4[fb + 12 * ii + k] = t;
        }
}

extern "C" void kernel_launch(void* const* d_in, const int* in_sizes, int n_in,
                              void* d_out, int out_size, void* d_ws, size_t ws_size,
                              hipStream_t stream) {
    const float* u0 = (const float*)d_in[0];
    const float* aw = (const float*)d_in[1];
    const float* bw = (const float*)d_in[2];
    float* out = (float*)d_out;

    const int B = in_sizes[0] / CELLS;   // 16384
    pde_heat_kernel<<<B / WPB, TPB, 0, stream>>>(u0, aw, bw, out);
}